// Round 13
// baseline (360.896 us; speedup 1.0000x reference)
//
#include <hip/hip_runtime.h>
#include <hip/hip_bf16.h>
#include <stdint.h>

#define B_ 4
#define N_ 2048
#define D_ 1024
#define K_ 16
#define MROWS (B_*N_)      // 8192
#define NC_ 64
#define CLEN_ (N_/NC_)     // 32

typedef unsigned short u16;
typedef __attribute__((ext_vector_type(8))) short bf16x8;
typedef __attribute__((ext_vector_type(8))) short short8;
typedef __attribute__((ext_vector_type(4))) float f32x4;

__device__ __forceinline__ u16 f2bf(float f) {
  uint32_t u = __float_as_uint(f);
  u = u + 0x7fffu + ((u >> 16) & 1u);
  return (u16)(u >> 16);
}
__device__ __forceinline__ float bf2f(u16 h) {
  uint32_t u = ((uint32_t)h) << 16;
  return __uint_as_float(u);
}
// fast f-gate: exp(logsigmoid(z)/16)
__device__ __forceinline__ float fgate(float z) {
  float ls = (z >= 0.0f) ? -__logf(1.0f + __expf(-z)) : (z - __logf(1.0f + __expf(z)));
  return __expf(ls * 0.0625f);
}

// ---------------- cast fp32 -> bf16 (vectorized) ----------------
__global__ __launch_bounds__(256) void cast_kernel(const float* __restrict__ in,
                                                   u16* __restrict__ out, int n) {
  int i = (blockIdx.x * 256 + threadIdx.x) * 4;
  if (i >= n) return;
  float4 v = *(const float4*)(in + i);
  ushort4 o;
  o.x = f2bf(v.x); o.y = f2bf(v.y); o.z = f2bf(v.z); o.w = f2bf(v.w);
  *(ushort4*)(out + i) = o;
}

// ---------------- prep: Wg = Wo*gamma (bf16), u = gamma.Wo^T, v = beta.Wo^T --
__global__ __launch_bounds__(256) void prep_kernel(const float* __restrict__ Wo,
                                                   const float* __restrict__ gamma,
                                                   const float* __restrict__ beta,
                                                   u16* __restrict__ Wg,
                                                   float* __restrict__ u,
                                                   float* __restrict__ v) {
  __shared__ float red[8];
  int c = blockIdx.x;
  int tid = threadIdx.x;
  int k0 = tid * 4;
  float4 wv = *(const float4*)(Wo + (size_t)c * D_ + k0);
  float4 g4 = *(const float4*)(gamma + k0);
  float4 b4 = *(const float4*)(beta + k0);
  ushort4 o;
  o.x = f2bf(wv.x * g4.x); o.y = f2bf(wv.y * g4.y);
  o.z = f2bf(wv.z * g4.z); o.w = f2bf(wv.w * g4.w);
  *(ushort4*)(Wg + (size_t)c * D_ + k0) = o;
  float us = wv.x * g4.x + wv.y * g4.y + wv.z * g4.z + wv.w * g4.w;
  float vs = wv.x * b4.x + wv.y * b4.y + wv.z * b4.z + wv.w * b4.w;
  for (int off = 32; off > 0; off >>= 1) {
    us += __shfl_xor(us, off);
    vs += __shfl_xor(vs, off);
  }
  int w = tid >> 6, l = tid & 63;
  if (l == 0) { red[w] = us; red[4 + w] = vs; }
  __syncthreads();
  if (tid == 0) {
    u[c] = red[0] + red[1] + red[2] + red[3];
    v[c] = red[4] + red[5] + red[6] + red[7];
  }
}

#define GL_LDS(gp, lp) \
  __builtin_amdgcn_global_load_lds( \
      (const __attribute__((address_space(1))) void*)(gp), \
      (__attribute__((address_space(3))) void*)(lp), 16, 0, 0)

#define WAITVM(n)  asm volatile("s_waitcnt vmcnt(" #n ")" ::: "memory")
#define SCHEDB()   __builtin_amdgcn_sched_barrier(0)

// ---------------- counted-vmcnt ring GEMM (bf16 outputs) ----------------
__global__ __launch_bounds__(512, 1) void ring_fused(const u16* __restrict__ A,
                                                     const u16* __restrict__ W0,
                                                     const u16* __restrict__ W1,
                                                     u16* __restrict__ C0,
                                                     u16* __restrict__ C1) {
  __shared__ __align__(16) u16 lds[3 * 24576];   // 147456 B

  const int tid = threadIdx.x;
  const int w = tid >> 6, l = tid & 63;
  const int wr = w >> 1, wc = w & 1;

  const int orig = blockIdx.x;
  const int wg = (orig & 7) * 64 + (orig >> 3);   // nwg = 512
  const int bm = wg / 16;
  const int bn = wg % 16;

  const u16* W;
  u16* C;
  int ncol0;
  if (bn >= 8) { W = W1; C = C1; ncol0 = (bn - 8) * 128; }
  else         { W = W0; C = C0; ncol0 = bn * 128; }

  const int sw = ((l & 7) ^ ((l >> 3) & 7)) * 8;
  const u16* aSrc = A + (size_t)(bm * 256 + w * 8 + (l >> 3)) * 1024 + sw;
  const u16* bSrc = W + (size_t)(ncol0 + w * 8 + (l >> 3)) * 1024 + sw;

#define STAGE_T(t, slot) do { \
    const int _sb = (slot) * 49152 + w * 1024; \
    _Pragma("unroll") \
    for (int j = 0; j < 4; ++j) \
      GL_LDS(aSrc + (size_t)j * 65536 + (t) * 64, (char*)lds + _sb + j * 8192); \
    _Pragma("unroll") \
    for (int j = 0; j < 2; ++j) \
      GL_LDS(bSrc + (size_t)j * 65536 + (t) * 64, (char*)lds + _sb + 32768 + j * 8192); \
  } while (0)

  const int sxe = (l & 7) << 3;
  const int klo = (l >> 4) * 8;
  const int aR0 = (wr * 64 + (l & 15)) * 64;
  const int bR0 = (wc * 64 + (l & 15)) * 64 + 16384;

  f32x4 acc[4][4] = {};

#define COMPUTE(slot) do { \
    const u16* S = lds + (slot) * 24576; \
    bf16x8 b0[4], a0[4], b1[4], a1[4]; \
    _Pragma("unroll") \
    for (int n = 0; n < 4; ++n) b0[n] = *(const bf16x8*)&S[bR0 + n * 1024 + (klo ^ sxe)]; \
    _Pragma("unroll") \
    for (int m = 0; m < 4; ++m) a0[m] = *(const bf16x8*)&S[aR0 + m * 1024 + (klo ^ sxe)]; \
    _Pragma("unroll") \
    for (int n = 0; n < 4; ++n) b1[n] = *(const bf16x8*)&S[bR0 + n * 1024 + ((klo + 32) ^ sxe)]; \
    _Pragma("unroll") \
    for (int m = 0; m < 4; ++m) a1[m] = *(const bf16x8*)&S[aR0 + m * 1024 + ((klo + 32) ^ sxe)]; \
    asm volatile("s_waitcnt lgkmcnt(8)" ::: "memory"); \
    SCHEDB(); \
    __builtin_amdgcn_s_setprio(1); \
    _Pragma("unroll") \
    for (int m = 0; m < 4; ++m) \
      _Pragma("unroll") \
      for (int n = 0; n < 4; ++n) \
        acc[m][n] = __builtin_amdgcn_mfma_f32_16x16x32_bf16(a0[m], b0[n], acc[m][n], 0, 0, 0); \
    __builtin_amdgcn_s_setprio(0); \
    asm volatile("s_waitcnt lgkmcnt(0)" ::: "memory"); \
    SCHEDB(); \
    __builtin_amdgcn_s_setprio(1); \
    _Pragma("unroll") \
    for (int m = 0; m < 4; ++m) \
      _Pragma("unroll") \
      for (int n = 0; n < 4; ++n) \
        acc[m][n] = __builtin_amdgcn_mfma_f32_16x16x32_bf16(a1[m], b1[n], acc[m][n], 0, 0, 0); \
    __builtin_amdgcn_s_setprio(0); \
  } while (0)

  STAGE_T(0, 0);
  STAGE_T(1, 1);
  WAITVM(6);
  __builtin_amdgcn_s_barrier();
  SCHEDB();

#pragma unroll
  for (int t = 0; t < 16; ++t) {
    if (t + 2 < 16) STAGE_T(t + 2, (t + 2) % 3);
    COMPUTE(t % 3);
    if (t < 15) {
      if (t == 14) WAITVM(0);
      else         WAITVM(6);
      __builtin_amdgcn_s_barrier();
      SCHEDB();
    }
  }

  const int orow0 = bm * 256 + wr * 64 + (l >> 4) * 4;
  const int ocol0 = ncol0 + wc * 64 + (l & 15);
#pragma unroll
  for (int m = 0; m < 4; ++m)
#pragma unroll
    for (int n = 0; n < 4; ++n)
#pragma unroll
      for (int r = 0; r < 4; ++r)
        C[(size_t)(orow0 + m * 16 + r) * 1024 + ocol0 + n * 16] = f2bf(acc[m][n][r]);
#undef STAGE_T
#undef COMPUTE
}

// ---------------- o-proj GEMM with fused-LN epilogue ----------------
__global__ __launch_bounds__(256) void gemm_bt_ln(const u16* __restrict__ A,
                                                  const u16* __restrict__ W,
                                                  float* __restrict__ C,
                                                  const float* __restrict__ rstd,
                                                  const float* __restrict__ mrs,
                                                  const float* __restrict__ u,
                                                  const float* __restrict__ v) {
  __shared__ u16 As[128 * 32];
  __shared__ u16 Bs[128 * 32];
  const int tid = threadIdx.x;
  const int w = tid >> 6, l = tid & 63;
  const int orig = blockIdx.x;
  const int swz = (orig & 7) * 64 + (orig >> 3);   // 512 blocks, bijective
  const int bm = swz >> 3, bn = swz & 7;
  const int wm = (w >> 1) * 64, wn = (w & 1) * 64;
  const int lr = l & 15, lk = (l >> 4) * 8;

  f32x4 acc[4][4] = {};

  for (int kt = 0; kt < 1024; kt += 32) {
#pragma unroll
    for (int j = 0; j < 2; ++j) {
      int ofs = w * 1024 + j * 4096;
      int gofs = ofs + l * 16;
      int row = gofs >> 6;
      int ke = (gofs & 63) >> 1;
      const u16* ga = A + (size_t)(bm * 128 + row) * 1024 + kt + ke;
      const u16* gb = W + (size_t)(bn * 128 + row) * 1024 + kt + ke;
      GL_LDS(ga, (char*)As + ofs);
      GL_LDS(gb, (char*)Bs + ofs);
    }
    __syncthreads();
    bf16x8 af[4], bfr[4];
#pragma unroll
    for (int i2 = 0; i2 < 4; ++i2) {
      af[i2]  = *(const bf16x8*)&As[(wm + i2 * 16 + lr) * 32 + lk];
      bfr[i2] = *(const bf16x8*)&Bs[(wn + i2 * 16 + lr) * 32 + lk];
    }
#pragma unroll
    for (int i2 = 0; i2 < 4; ++i2)
#pragma unroll
      for (int j2 = 0; j2 < 4; ++j2)
        acc[i2][j2] = __builtin_amdgcn_mfma_f32_16x16x32_bf16(af[i2], bfr[j2], acc[i2][j2], 0, 0, 0);
    __syncthreads();
  }

  const int orow0 = bm * 128 + wm + (l >> 4) * 4;
  const int ocol0 = bn * 128 + wn + (l & 15);
#pragma unroll
  for (int i2 = 0; i2 < 4; ++i2) {
#pragma unroll
    for (int j2 = 0; j2 < 4; ++j2) {
      int col = ocol0 + j2 * 16;
      float uc = u[col], vc = v[col];
#pragma unroll
      for (int r = 0; r < 4; ++r) {
        int row = orow0 + i2 * 16 + r;
        C[(size_t)row * 1024 + col] = rstd[row] * acc[i2][j2][r] + mrs[row] * uc + vc;
      }
    }
  }
}

// ---------------- e/s via MFMA ----------------
__global__ __launch_bounds__(256) void es_mfma(const u16* __restrict__ xb,
                                               const float* __restrict__ We,
                                               const float* __restrict__ Ws,
                                               float* __restrict__ e,
                                               float* __restrict__ s) {
  __shared__ __align__(16) u16 Bsm[32 * 1024];     // 64 KB persistent
  __shared__ __align__(16) u16 Asl[2][64 * 128];   // 2 x 16 KB dbuf

  const int tid = threadIdx.x;
  const int w = tid >> 6, l = tid & 63;
  const int bm = blockIdx.x;                       // 0..127

#pragma unroll
  for (int q = 0; q < 16; ++q) {
    int g = q * 256 + tid;
    int n = g >> 7;
    int c = g & 127;
    const float* src = (n < 16 ? We + (size_t)n * 1024 : Ws + (size_t)(n - 16) * 1024) + c * 8;
    float4 v0 = *(const float4*)(src);
    float4 v1 = *(const float4*)(src + 4);
    short8 o;
    o[0] = (short)f2bf(v0.x); o[1] = (short)f2bf(v0.y);
    o[2] = (short)f2bf(v0.z); o[3] = (short)f2bf(v0.w);
    o[4] = (short)f2bf(v1.x); o[5] = (short)f2bf(v1.y);
    o[6] = (short)f2bf(v1.z); o[7] = (short)f2bf(v1.w);
    *(short8*)&Bsm[(size_t)n * 1024 + (size_t)(c ^ (n & 15)) * 8] = o;
  }

  const int arow_par = w * 4 + (l >> 4);
  const int csrc = (l & 15) ^ arow_par;

#define ESTAGE(t, buf) do { \
    _Pragma("unroll") \
    for (int j = 0; j < 4; ++j) { \
      const u16* gp = xb + (size_t)(bm * 64 + j * 16 + arow_par) * 1024 + (t) * 128 + csrc * 8; \
      GL_LDS(gp, (char*)&Asl[(buf)][0] + j * 4096 + w * 1024); \
    } \
  } while (0)

  f32x4 acc[2] = {};

  ESTAGE(0, 0);
  __syncthreads();

#pragma unroll
  for (int t = 0; t < 8; ++t) {
    if (t) { WAITVM(0); __builtin_amdgcn_s_barrier(); }
    if (t + 1 < 8) ESTAGE(t + 1, (t + 1) & 1);
    const int buf = t & 1;
#pragma unroll
    for (int ks = 0; ks < 4; ++ks) {
      bf16x8 af = *(const bf16x8*)&Asl[buf][(size_t)(w * 16 + (l & 15)) * 128 +
                                           (size_t)(((ks * 4 + (l >> 4)) ^ (l & 15))) * 8];
      bf16x8 b0 = *(const bf16x8*)&Bsm[(size_t)(0 + (l & 15)) * 1024 +
                                       (size_t)(((t * 16 + ks * 4 + (l >> 4)) ^ (l & 15))) * 8];
      bf16x8 b1 = *(const bf16x8*)&Bsm[(size_t)(16 + (l & 15)) * 1024 +
                                       (size_t)(((t * 16 + ks * 4 + (l >> 4)) ^ (l & 15))) * 8];
      acc[0] = __builtin_amdgcn_mfma_f32_16x16x32_bf16(af, b0, acc[0], 0, 0, 0);
      acc[1] = __builtin_amdgcn_mfma_f32_16x16x32_bf16(af, b1, acc[1], 0, 0, 0);
    }
  }

  const int orow = bm * 64 + w * 16 + (l >> 4) * 4;
  const int ocol = l & 15;
#pragma unroll
  for (int r = 0; r < 4; ++r) {
    e[(size_t)(orow + r) * K_ + ocol] = acc[0][r];
    s[(size_t)(orow + r) * K_ + ocol] = acc[1][r];
  }
#undef ESTAGE
}

// ---------------- scan pass1 (NC=64, CLEN=32, batch-16 prefetch) ----------
__global__ __launch_bounds__(256, 4) void scan_pass1(const u16* __restrict__ ibb,
                                                     const u16* __restrict__ zbb,
                                                     const float* __restrict__ ebuf,
                                                     float* __restrict__ Asc,
                                                     float* __restrict__ Psc) {
  __shared__ float els[CLEN_ * K_];   // 2 KB
  int bid = blockIdx.x;
  int dq = bid & 3, c = (bid >> 2) % NC_, b = bid / (NC_ * 4);
  int d = dq * 256 + threadIdx.x;
  int t0 = c * CLEN_;

  if (threadIdx.x < CLEN_ * K_ / 4) {
    *(float4*)&els[threadIdx.x * 4] =
        *(const float4*)(ebuf + ((size_t)b * N_ + t0) * K_ + threadIdx.x * 4);
  }
  __syncthreads();

  float m[K_];
#pragma unroll
  for (int k = 0; k < K_; ++k) m[k] = 0.f;
  float p = 1.0f;
  const u16* ip = ibb + ((size_t)b * N_ + t0) * D_ + d;
  const u16* zp = zbb + ((size_t)b * N_ + t0) * D_ + d;

#pragma unroll 1
  for (int tb = 0; tb < CLEN_; tb += 16) {
    float iv[16], zv[16];
#pragma unroll
    for (int j = 0; j < 16; ++j) iv[j] = bf2f(ip[(size_t)(tb + j) * D_]);
#pragma unroll
    for (int j = 0; j < 16; ++j) zv[j] = bf2f(zp[(size_t)(tb + j) * D_]);
#pragma unroll
    for (int j = 0; j < 16; ++j) {
      float ft = fgate(zv[j]);
      p *= ft;
      const float* ec = &els[(tb + j) * K_];
#pragma unroll
      for (int k = 0; k < K_; ++k) m[k] = ft * m[k] + ec[k] * iv[j];
    }
  }

  float* ap = Asc + (((size_t)b * NC_ + c) * K_) * D_ + d;
#pragma unroll
  for (int k = 0; k < K_; ++k) ap[(size_t)k * D_] = m[k];
  Psc[((size_t)b * NC_ + c) * D_ + d] = p;
}

// ---------------- scan pass2: in-place chunk combine (NC=64) --------------
__global__ __launch_bounds__(256, 4) void scan_pass2(float* __restrict__ Asc,
                                                     const float* __restrict__ Psc) {
  int idx = blockIdx.x * 256 + threadIdx.x;
  int d = idx & (D_ - 1);
  int k = (idx >> 10) & (K_ - 1);
  int b = idx >> 14;
  float M = 0.f;
#pragma unroll 1
  for (int cb = 0; cb < NC_; cb += 8) {
    float a[8], pp[8];
#pragma unroll
    for (int j = 0; j < 8; ++j) {
      size_t base = (((size_t)b * NC_ + cb + j) * K_ + k) * D_ + d;
      a[j] = Asc[base];
      pp[j] = Psc[((size_t)b * NC_ + cb + j) * D_ + d];
    }
#pragma unroll
    for (int j = 0; j < 8; ++j) {
      size_t base = (((size_t)b * NC_ + cb + j) * K_ + k) * D_ + d;
      Asc[base] = M;                // in-place: chunk-start state
      M = pp[j] * M + a[j];
    }
  }
}

// ---------------- scan pass3 (batch-16 prefetch) ----------------
__global__ __launch_bounds__(256, 4) void scan_pass3(const u16* __restrict__ ibb,
                                                     const u16* __restrict__ zbb,
                                                     const float* __restrict__ ebuf,
                                                     const float* __restrict__ sbuf,
                                                     const float* __restrict__ Ssc,
                                                     u16* __restrict__ ybb) {
  __shared__ float els[CLEN_ * K_];   // 2 KB
  __shared__ float sls[CLEN_ * K_];   // 2 KB
  int bid = blockIdx.x;
  int dq = bid & 3, c = (bid >> 2) % NC_, b = bid / (NC_ * 4);
  int d = dq * 256 + threadIdx.x;
  int t0 = c * CLEN_;

  if (threadIdx.x < CLEN_ * K_ / 4) {
    *(float4*)&els[threadIdx.x * 4] =
        *(const float4*)(ebuf + ((size_t)b * N_ + t0) * K_ + threadIdx.x * 4);
  } else if (threadIdx.x < CLEN_ * K_ / 2) {
    int q = threadIdx.x - CLEN_ * K_ / 4;
    *(float4*)&sls[q * 4] =
        *(const float4*)(sbuf + ((size_t)b * N_ + t0) * K_ + q * 4);
  }

  float m[K_];
  const float* sp0 = Ssc + (((size_t)b * NC_ + c) * K_) * D_ + d;
#pragma unroll
  for (int k = 0; k < K_; ++k) m[k] = sp0[(size_t)k * D_];
  __syncthreads();

  const u16* ip = ibb + ((size_t)b * N_ + t0) * D_ + d;
  const u16* zp = zbb + ((size_t)b * N_ + t0) * D_ + d;
  u16* yp = ybb + ((size_t)b * N_ + t0) * D_ + d;

#pragma unroll 1
  for (int tb = 0; tb < CLEN_; tb += 16) {
    float iv[16], zv[16];
#pragma unroll
    for (int j = 0; j < 16; ++j) iv[j] = bf2f(ip[(size_t)(tb + j) * D_]);
#pragma unroll
    for (int j = 0; j < 16; ++j) zv[j] = bf2f(zp[(size_t)(tb + j) * D_]);
#pragma unroll
    for (int j = 0; j < 16; ++j) {
      float ft = fgate(zv[j]);
      const float* ec = &els[(tb + j) * K_];
      const float* sc = &sls[(tb + j) * K_];
      float y = 0.f;
#pragma unroll
      for (int k = 0; k < K_; ++k) {
        m[k] = ft * m[k] + ec[k] * iv[j];
        y += sc[k] * m[k];
      }
      yp[(size_t)(tb + j) * D_] = f2bf(y);
    }
  }
}

// ---------------- row stats: rstd & -mu*rstd per row (1 wave/row) ---------
__global__ __launch_bounds__(256) void rowstat(const u16* __restrict__ y,
                                               float* __restrict__ rstd,
                                               float* __restrict__ mrs) {
  int row = blockIdx.x * 4 + (threadIdx.x >> 6);
  int l = threadIdx.x & 63;
  const u16* yr = y + (size_t)row * D_;
  float sum = 0.f, sq = 0.f;
#pragma unroll
  for (int j = 0; j < 2; ++j) {
    short8 raw = *(const short8*)(yr + l * 16 + j * 8);
#pragma unroll
    for (int q = 0; q < 8; ++q) {
      float f = bf2f((u16)raw[q]);
      sum += f;
      sq += f * f;
    }
  }
  for (int off = 32; off > 0; off >>= 1) {
    sum += __shfl_xor(sum, off);
    sq  += __shfl_xor(sq, off);
  }
  if (l == 0) {
    float mu = sum * (1.0f / D_);
    float var = sq * (1.0f / D_) - mu * mu;
    float rs = rsqrtf(var + 1e-5f);
    rstd[row] = rs;
    mrs[row] = -mu * rs;
  }
}

extern "C" void kernel_launch(void* const* d_in, const int* in_sizes, int n_in,
                              void* d_out, int out_size, void* d_ws, size_t ws_size,
                              hipStream_t stream) {
  const float* x     = (const float*)d_in[0];
  const float* Wi    = (const float*)d_in[1];
  const float* We    = (const float*)d_in[2];
  const float* Wf    = (const float*)d_in[3];
  const float* Ws    = (const float*)d_in[4];
  const float* gamma = (const float*)d_in[5];
  const float* beta  = (const float*)d_in[6];
  const float* Wo    = (const float*)d_in[7];
  float* out = (float*)d_out;

  char* p = (char*)d_ws;
  u16* xb   = (u16*)p;  p += (size_t)MROWS * D_ * 2;       // 16 MB
  u16* wib  = (u16*)p;  p += (size_t)D_ * D_ * 2;          // 2 MB
  u16* wfb  = (u16*)p;  p += (size_t)D_ * D_ * 2;          // 2 MB
  u16* wgb  = (u16*)p;  p += (size_t)D_ * D_ * 2;          // 2 MB (Wo*gamma)
  u16* ibb  = (u16*)p;  p += (size_t)MROWS * D_ * 2;       // 16 MB
  u16* zbb  = (u16*)p;  p += (size_t)MROWS * D_ * 2;       // 16 MB
  u16* ybb  = (u16*)p;  p += (size_t)MROWS * D_ * 2;       // 16 MB
  float* ebuf = (float*)p; p += (size_t)MROWS * K_ * 4;    // 512 KB
  float* sbuf = (float*)p; p += (size_t)MROWS * K_ * 4;    // 512 KB
  float* Asc  = (float*)p; p += (size_t)B_ * NC_ * K_ * D_ * 4;  // 16 MB
  float* Psc  = (float*)p; p += (size_t)B_ * NC_ * D_ * 4;       // 1 MB
  float* rstd = (float*)p; p += (size_t)MROWS * 4;         // 32 KB
  float* mrs  = (float*)p; p += (size_t)MROWS * 4;         // 32 KB
  float* ub   = (float*)p; p += (size_t)D_ * 4;            // 4 KB
  float* vb   = (float*)p; p += (size_t)D_ * 4;            // 4 KB

  cast_kernel<<<MROWS * D_ / 1024, 256, 0, stream>>>(x, xb, MROWS * D_);
  cast_kernel<<<D_ * D_ / 1024, 256, 0, stream>>>(Wi, wib, D_ * D_);
  cast_kernel<<<D_ * D_ / 1024, 256, 0, stream>>>(Wf, wfb, D_ * D_);
  prep_kernel<<<D_, 256, 0, stream>>>(Wo, gamma, beta, wgb, ub, vb);

  ring_fused<<<512, 512, 0, stream>>>(xb, wib, wfb, ibb, zbb);

  es_mfma<<<MROWS / 64, 256, 0, stream>>>(xb, We, Ws, ebuf, sbuf);

  scan_pass1<<<B_ * NC_ * 4, 256, 0, stream>>>(ibb, zbb, ebuf, Asc, Psc);
  scan_pass2<<<B_ * K_ * D_ / 256, 256, 0, stream>>>(Asc, Psc);
  scan_pass3<<<B_ * NC_ * 4, 256, 0, stream>>>(ibb, zbb, ebuf, sbuf, Asc, ybb);

  rowstat<<<MROWS / 4, 256, 0, stream>>>(ybb, rstd, mrs);

  gemm_bt_ln<<<512, 256, 0, stream>>>(ybb, wgb, out, rstd, mrs, ub, vb);
}

// Round 14
// 166.701 us; speedup vs baseline: 2.1649x; 2.1649x over previous
//
#include <hip/hip_runtime.h>
#include <hip/hip_bf16.h>
#include <stdint.h>

#define B_ 4
#define N_ 2048
#define D_ 1024
#define K_ 16
#define MROWS (B_*N_)      // 8192
#define NC_ 64
#define CLEN_ (N_/NC_)     // 32

typedef unsigned short u16;
typedef __attribute__((ext_vector_type(8))) short bf16x8;
typedef __attribute__((ext_vector_type(8))) short short8;
typedef __attribute__((ext_vector_type(4))) float f32x4;

__device__ __forceinline__ u16 f2bf(float f) {
  uint32_t u = __float_as_uint(f);
  u = u + 0x7fffu + ((u >> 16) & 1u);
  return (u16)(u >> 16);
}
__device__ __forceinline__ float bf2f(u16 h) {
  uint32_t u = ((uint32_t)h) << 16;
  return __uint_as_float(u);
}
// fast f-gate: exp(logsigmoid(z)/16)
__device__ __forceinline__ float fgate(float z) {
  float ls = (z >= 0.0f) ? -__logf(1.0f + __expf(-z)) : (z - __logf(1.0f + __expf(z)));
  return __expf(ls * 0.0625f);
}

// ---------------- cast fp32 -> bf16 (vectorized) ----------------
__global__ __launch_bounds__(256) void cast_kernel(const float* __restrict__ in,
                                                   u16* __restrict__ out, int n) {
  int i = (blockIdx.x * 256 + threadIdx.x) * 4;
  if (i >= n) return;
  float4 v = *(const float4*)(in + i);
  ushort4 o;
  o.x = f2bf(v.x); o.y = f2bf(v.y); o.z = f2bf(v.z); o.w = f2bf(v.w);
  *(ushort4*)(out + i) = o;
}

// ---------------- prep: Wg = Wo*gamma (bf16), u = gamma.Wo^T, v = beta.Wo^T --
__global__ __launch_bounds__(256) void prep_kernel(const float* __restrict__ Wo,
                                                   const float* __restrict__ gamma,
                                                   const float* __restrict__ beta,
                                                   u16* __restrict__ Wg,
                                                   float* __restrict__ u,
                                                   float* __restrict__ v) {
  __shared__ float red[8];
  int c = blockIdx.x;
  int tid = threadIdx.x;
  int k0 = tid * 4;
  float4 wv = *(const float4*)(Wo + (size_t)c * D_ + k0);
  float4 g4 = *(const float4*)(gamma + k0);
  float4 b4 = *(const float4*)(beta + k0);
  ushort4 o;
  o.x = f2bf(wv.x * g4.x); o.y = f2bf(wv.y * g4.y);
  o.z = f2bf(wv.z * g4.z); o.w = f2bf(wv.w * g4.w);
  *(ushort4*)(Wg + (size_t)c * D_ + k0) = o;
  float us = wv.x * g4.x + wv.y * g4.y + wv.z * g4.z + wv.w * g4.w;
  float vs = wv.x * b4.x + wv.y * b4.y + wv.z * b4.z + wv.w * b4.w;
  for (int off = 32; off > 0; off >>= 1) {
    us += __shfl_xor(us, off);
    vs += __shfl_xor(vs, off);
  }
  int w = tid >> 6, l = tid & 63;
  if (l == 0) { red[w] = us; red[4 + w] = vs; }
  __syncthreads();
  if (tid == 0) {
    u[c] = red[0] + red[1] + red[2] + red[3];
    v[c] = red[4] + red[5] + red[6] + red[7];
  }
}

#define GL_LDS(gp, lp) \
  __builtin_amdgcn_global_load_lds( \
      (const __attribute__((address_space(1))) void*)(gp), \
      (__attribute__((address_space(3))) void*)(lp), 16, 0, 0)

#define WAITVM(n)  asm volatile("s_waitcnt vmcnt(" #n ")" ::: "memory")
#define SCHEDB()   __builtin_amdgcn_sched_barrier(0)

// ---------------- counted-vmcnt ring GEMM (bf16 outputs) ----------------
__global__ __launch_bounds__(512, 1) void ring_fused(const u16* __restrict__ A,
                                                     const u16* __restrict__ W0,
                                                     const u16* __restrict__ W1,
                                                     u16* __restrict__ C0,
                                                     u16* __restrict__ C1) {
  __shared__ __align__(16) u16 lds[3 * 24576];   // 147456 B

  const int tid = threadIdx.x;
  const int w = tid >> 6, l = tid & 63;
  const int wr = w >> 1, wc = w & 1;

  const int orig = blockIdx.x;
  const int wg = (orig & 7) * 64 + (orig >> 3);   // nwg = 512
  const int bm = wg / 16;
  const int bn = wg % 16;

  const u16* W;
  u16* C;
  int ncol0;
  if (bn >= 8) { W = W1; C = C1; ncol0 = (bn - 8) * 128; }
  else         { W = W0; C = C0; ncol0 = bn * 128; }

  const int sw = ((l & 7) ^ ((l >> 3) & 7)) * 8;
  const u16* aSrc = A + (size_t)(bm * 256 + w * 8 + (l >> 3)) * 1024 + sw;
  const u16* bSrc = W + (size_t)(ncol0 + w * 8 + (l >> 3)) * 1024 + sw;

#define STAGE_T(t, slot) do { \
    const int _sb = (slot) * 49152 + w * 1024; \
    _Pragma("unroll") \
    for (int j = 0; j < 4; ++j) \
      GL_LDS(aSrc + (size_t)j * 65536 + (t) * 64, (char*)lds + _sb + j * 8192); \
    _Pragma("unroll") \
    for (int j = 0; j < 2; ++j) \
      GL_LDS(bSrc + (size_t)j * 65536 + (t) * 64, (char*)lds + _sb + 32768 + j * 8192); \
  } while (0)

  const int sxe = (l & 7) << 3;
  const int klo = (l >> 4) * 8;
  const int aR0 = (wr * 64 + (l & 15)) * 64;
  const int bR0 = (wc * 64 + (l & 15)) * 64 + 16384;

  f32x4 acc[4][4] = {};

#define COMPUTE(slot) do { \
    const u16* S = lds + (slot) * 24576; \
    bf16x8 b0[4], a0[4], b1[4], a1[4]; \
    _Pragma("unroll") \
    for (int n = 0; n < 4; ++n) b0[n] = *(const bf16x8*)&S[bR0 + n * 1024 + (klo ^ sxe)]; \
    _Pragma("unroll") \
    for (int m = 0; m < 4; ++m) a0[m] = *(const bf16x8*)&S[aR0 + m * 1024 + (klo ^ sxe)]; \
    _Pragma("unroll") \
    for (int n = 0; n < 4; ++n) b1[n] = *(const bf16x8*)&S[bR0 + n * 1024 + ((klo + 32) ^ sxe)]; \
    _Pragma("unroll") \
    for (int m = 0; m < 4; ++m) a1[m] = *(const bf16x8*)&S[aR0 + m * 1024 + ((klo + 32) ^ sxe)]; \
    asm volatile("s_waitcnt lgkmcnt(8)" ::: "memory"); \
    SCHEDB(); \
    __builtin_amdgcn_s_setprio(1); \
    _Pragma("unroll") \
    for (int m = 0; m < 4; ++m) \
      _Pragma("unroll") \
      for (int n = 0; n < 4; ++n) \
        acc[m][n] = __builtin_amdgcn_mfma_f32_16x16x32_bf16(a0[m], b0[n], acc[m][n], 0, 0, 0); \
    __builtin_amdgcn_s_setprio(0); \
    asm volatile("s_waitcnt lgkmcnt(0)" ::: "memory"); \
    SCHEDB(); \
    __builtin_amdgcn_s_setprio(1); \
    _Pragma("unroll") \
    for (int m = 0; m < 4; ++m) \
      _Pragma("unroll") \
      for (int n = 0; n < 4; ++n) \
        acc[m][n] = __builtin_amdgcn_mfma_f32_16x16x32_bf16(a1[m], b1[n], acc[m][n], 0, 0, 0); \
    __builtin_amdgcn_s_setprio(0); \
  } while (0)

  STAGE_T(0, 0);
  STAGE_T(1, 1);
  WAITVM(6);
  __builtin_amdgcn_s_barrier();
  SCHEDB();

#pragma unroll
  for (int t = 0; t < 16; ++t) {
    if (t + 2 < 16) STAGE_T(t + 2, (t + 2) % 3);
    COMPUTE(t % 3);
    if (t < 15) {
      if (t == 14) WAITVM(0);
      else         WAITVM(6);
      __builtin_amdgcn_s_barrier();
      SCHEDB();
    }
  }

  const int orow0 = bm * 256 + wr * 64 + (l >> 4) * 4;
  const int ocol0 = ncol0 + wc * 64 + (l & 15);
#pragma unroll
  for (int m = 0; m < 4; ++m)
#pragma unroll
    for (int n = 0; n < 4; ++n)
#pragma unroll
      for (int r = 0; r < 4; ++r)
        C[(size_t)(orow0 + m * 16 + r) * 1024 + ocol0 + n * 16] = f2bf(acc[m][n][r]);
#undef STAGE_T
#undef COMPUTE
}

// ---------------- o-proj GEMM with fused-LN epilogue ----------------
__global__ __launch_bounds__(256) void gemm_bt_ln(const u16* __restrict__ A,
                                                  const u16* __restrict__ W,
                                                  float* __restrict__ C,
                                                  const float* __restrict__ rstd,
                                                  const float* __restrict__ mrs,
                                                  const float* __restrict__ u,
                                                  const float* __restrict__ v) {
  __shared__ u16 As[128 * 32];
  __shared__ u16 Bs[128 * 32];
  const int tid = threadIdx.x;
  const int w = tid >> 6, l = tid & 63;
  const int orig = blockIdx.x;
  const int swz = (orig & 7) * 64 + (orig >> 3);   // 512 blocks, bijective
  const int bm = swz >> 3, bn = swz & 7;
  const int wm = (w >> 1) * 64, wn = (w & 1) * 64;
  const int lr = l & 15, lk = (l >> 4) * 8;

  f32x4 acc[4][4] = {};

  for (int kt = 0; kt < 1024; kt += 32) {
#pragma unroll
    for (int j = 0; j < 2; ++j) {
      int ofs = w * 1024 + j * 4096;
      int gofs = ofs + l * 16;
      int row = gofs >> 6;
      int ke = (gofs & 63) >> 1;
      const u16* ga = A + (size_t)(bm * 128 + row) * 1024 + kt + ke;
      const u16* gb = W + (size_t)(bn * 128 + row) * 1024 + kt + ke;
      GL_LDS(ga, (char*)As + ofs);
      GL_LDS(gb, (char*)Bs + ofs);
    }
    __syncthreads();
    bf16x8 af[4], bfr[4];
#pragma unroll
    for (int i2 = 0; i2 < 4; ++i2) {
      af[i2]  = *(const bf16x8*)&As[(wm + i2 * 16 + lr) * 32 + lk];
      bfr[i2] = *(const bf16x8*)&Bs[(wn + i2 * 16 + lr) * 32 + lk];
    }
#pragma unroll
    for (int i2 = 0; i2 < 4; ++i2)
#pragma unroll
      for (int j2 = 0; j2 < 4; ++j2)
        acc[i2][j2] = __builtin_amdgcn_mfma_f32_16x16x32_bf16(af[i2], bfr[j2], acc[i2][j2], 0, 0, 0);
    __syncthreads();
  }

  const int orow0 = bm * 128 + wm + (l >> 4) * 4;
  const int ocol0 = bn * 128 + wn + (l & 15);
#pragma unroll
  for (int i2 = 0; i2 < 4; ++i2) {
#pragma unroll
    for (int j2 = 0; j2 < 4; ++j2) {
      int col = ocol0 + j2 * 16;
      float uc = u[col], vc = v[col];
#pragma unroll
      for (int r = 0; r < 4; ++r) {
        int row = orow0 + i2 * 16 + r;
        C[(size_t)row * 1024 + col] = rstd[row] * acc[i2][j2][r] + mrs[row] * uc + vc;
      }
    }
  }
}

// ---------------- e/s via MFMA ----------------
__global__ __launch_bounds__(256) void es_mfma(const u16* __restrict__ xb,
                                               const float* __restrict__ We,
                                               const float* __restrict__ Ws,
                                               float* __restrict__ e,
                                               float* __restrict__ s) {
  __shared__ __align__(16) u16 Bsm[32 * 1024];     // 64 KB persistent
  __shared__ __align__(16) u16 Asl[2][64 * 128];   // 2 x 16 KB dbuf

  const int tid = threadIdx.x;
  const int w = tid >> 6, l = tid & 63;
  const int bm = blockIdx.x;                       // 0..127

#pragma unroll
  for (int q = 0; q < 16; ++q) {
    int g = q * 256 + tid;
    int n = g >> 7;
    int c = g & 127;
    const float* src = (n < 16 ? We + (size_t)n * 1024 : Ws + (size_t)(n - 16) * 1024) + c * 8;
    float4 v0 = *(const float4*)(src);
    float4 v1 = *(const float4*)(src + 4);
    short8 o;
    o[0] = (short)f2bf(v0.x); o[1] = (short)f2bf(v0.y);
    o[2] = (short)f2bf(v0.z); o[3] = (short)f2bf(v0.w);
    o[4] = (short)f2bf(v1.x); o[5] = (short)f2bf(v1.y);
    o[6] = (short)f2bf(v1.z); o[7] = (short)f2bf(v1.w);
    *(short8*)&Bsm[(size_t)n * 1024 + (size_t)(c ^ (n & 15)) * 8] = o;
  }

  const int arow_par = w * 4 + (l >> 4);
  const int csrc = (l & 15) ^ arow_par;

#define ESTAGE(t, buf) do { \
    _Pragma("unroll") \
    for (int j = 0; j < 4; ++j) { \
      const u16* gp = xb + (size_t)(bm * 64 + j * 16 + arow_par) * 1024 + (t) * 128 + csrc * 8; \
      GL_LDS(gp, (char*)&Asl[(buf)][0] + j * 4096 + w * 1024); \
    } \
  } while (0)

  f32x4 acc[2] = {};

  ESTAGE(0, 0);
  __syncthreads();

#pragma unroll
  for (int t = 0; t < 8; ++t) {
    if (t) { WAITVM(0); __builtin_amdgcn_s_barrier(); }
    if (t + 1 < 8) ESTAGE(t + 1, (t + 1) & 1);
    const int buf = t & 1;
#pragma unroll
    for (int ks = 0; ks < 4; ++ks) {
      bf16x8 af = *(const bf16x8*)&Asl[buf][(size_t)(w * 16 + (l & 15)) * 128 +
                                           (size_t)(((ks * 4 + (l >> 4)) ^ (l & 15))) * 8];
      bf16x8 b0 = *(const bf16x8*)&Bsm[(size_t)(0 + (l & 15)) * 1024 +
                                       (size_t)(((t * 16 + ks * 4 + (l >> 4)) ^ (l & 15))) * 8];
      bf16x8 b1 = *(const bf16x8*)&Bsm[(size_t)(16 + (l & 15)) * 1024 +
                                       (size_t)(((t * 16 + ks * 4 + (l >> 4)) ^ (l & 15))) * 8];
      acc[0] = __builtin_amdgcn_mfma_f32_16x16x32_bf16(af, b0, acc[0], 0, 0, 0);
      acc[1] = __builtin_amdgcn_mfma_f32_16x16x32_bf16(af, b1, acc[1], 0, 0, 0);
    }
  }

  const int orow = bm * 64 + w * 16 + (l >> 4) * 4;
  const int ocol = l & 15;
#pragma unroll
  for (int r = 0; r < 4; ++r) {
    e[(size_t)(orow + r) * K_ + ocol] = acc[0][r];
    s[(size_t)(orow + r) * K_ + ocol] = acc[1][r];
  }
#undef ESTAGE
}

// ---------------- scan pass1 (NC=64, CLEN=32, batch-8, R11-exact) ---------
__global__ __launch_bounds__(256, 4) void scan_pass1(const u16* __restrict__ ibb,
                                                     const u16* __restrict__ zbb,
                                                     const float* __restrict__ ebuf,
                                                     float* __restrict__ Asc,
                                                     float* __restrict__ Psc) {
  __shared__ float els[CLEN_ * K_];   // 2 KB
  int bid = blockIdx.x;
  int dq = bid & 3, c = (bid >> 2) % NC_, b = bid / (NC_ * 4);
  int d = dq * 256 + threadIdx.x;
  int t0 = c * CLEN_;

  if (threadIdx.x < CLEN_ * K_ / 4) {
    *(float4*)&els[threadIdx.x * 4] =
        *(const float4*)(ebuf + ((size_t)b * N_ + t0) * K_ + threadIdx.x * 4);
  }
  __syncthreads();

  float m[K_];
#pragma unroll
  for (int k = 0; k < K_; ++k) m[k] = 0.f;
  float p = 1.0f;
  const u16* ip = ibb + ((size_t)b * N_ + t0) * D_ + d;
  const u16* zp = zbb + ((size_t)b * N_ + t0) * D_ + d;

#pragma unroll 1
  for (int tb = 0; tb < CLEN_; tb += 8) {
    float iv[8], zv[8];
#pragma unroll
    for (int j = 0; j < 8; ++j) iv[j] = bf2f(ip[(size_t)(tb + j) * D_]);
#pragma unroll
    for (int j = 0; j < 8; ++j) zv[j] = bf2f(zp[(size_t)(tb + j) * D_]);
#pragma unroll
    for (int j = 0; j < 8; ++j) {
      float ft = fgate(zv[j]);
      p *= ft;
      const float* ec = &els[(tb + j) * K_];
#pragma unroll
      for (int k = 0; k < K_; ++k) m[k] = ft * m[k] + ec[k] * iv[j];
    }
  }

  float* ap = Asc + (((size_t)b * NC_ + c) * K_) * D_ + d;
#pragma unroll
  for (int k = 0; k < K_; ++k) ap[(size_t)k * D_] = m[k];
  Psc[((size_t)b * NC_ + c) * D_ + d] = p;
}

// ---------------- scan pass2: in-place chunk combine (NC=64) --------------
__global__ __launch_bounds__(256, 4) void scan_pass2(float* __restrict__ Asc,
                                                     const float* __restrict__ Psc) {
  int idx = blockIdx.x * 256 + threadIdx.x;
  int d = idx & (D_ - 1);
  int k = (idx >> 10) & (K_ - 1);
  int b = idx >> 14;
  float M = 0.f;
#pragma unroll 1
  for (int cb = 0; cb < NC_; cb += 8) {
    float a[8], pp[8];
#pragma unroll
    for (int j = 0; j < 8; ++j) {
      size_t base = (((size_t)b * NC_ + cb + j) * K_ + k) * D_ + d;
      a[j] = Asc[base];
      pp[j] = Psc[((size_t)b * NC_ + cb + j) * D_ + d];
    }
#pragma unroll
    for (int j = 0; j < 8; ++j) {
      size_t base = (((size_t)b * NC_ + cb + j) * K_ + k) * D_ + d;
      Asc[base] = M;                // in-place: chunk-start state
      M = pp[j] * M + a[j];
    }
  }
}

// ---------------- scan pass3 (batch-8, R11-exact) ----------------
__global__ __launch_bounds__(256, 4) void scan_pass3(const u16* __restrict__ ibb,
                                                     const u16* __restrict__ zbb,
                                                     const float* __restrict__ ebuf,
                                                     const float* __restrict__ sbuf,
                                                     const float* __restrict__ Ssc,
                                                     u16* __restrict__ ybb) {
  __shared__ float els[CLEN_ * K_];   // 2 KB
  __shared__ float sls[CLEN_ * K_];   // 2 KB
  int bid = blockIdx.x;
  int dq = bid & 3, c = (bid >> 2) % NC_, b = bid / (NC_ * 4);
  int d = dq * 256 + threadIdx.x;
  int t0 = c * CLEN_;

  if (threadIdx.x < CLEN_ * K_ / 4) {
    *(float4*)&els[threadIdx.x * 4] =
        *(const float4*)(ebuf + ((size_t)b * N_ + t0) * K_ + threadIdx.x * 4);
  } else if (threadIdx.x < CLEN_ * K_ / 2) {
    int q = threadIdx.x - CLEN_ * K_ / 4;
    *(float4*)&sls[q * 4] =
        *(const float4*)(sbuf + ((size_t)b * N_ + t0) * K_ + q * 4);
  }

  float m[K_];
  const float* sp0 = Ssc + (((size_t)b * NC_ + c) * K_) * D_ + d;
#pragma unroll
  for (int k = 0; k < K_; ++k) m[k] = sp0[(size_t)k * D_];
  __syncthreads();

  const u16* ip = ibb + ((size_t)b * N_ + t0) * D_ + d;
  const u16* zp = zbb + ((size_t)b * N_ + t0) * D_ + d;
  u16* yp = ybb + ((size_t)b * N_ + t0) * D_ + d;

#pragma unroll 1
  for (int tb = 0; tb < CLEN_; tb += 8) {
    float iv[8], zv[8];
#pragma unroll
    for (int j = 0; j < 8; ++j) iv[j] = bf2f(ip[(size_t)(tb + j) * D_]);
#pragma unroll
    for (int j = 0; j < 8; ++j) zv[j] = bf2f(zp[(size_t)(tb + j) * D_]);
#pragma unroll
    for (int j = 0; j < 8; ++j) {
      float ft = fgate(zv[j]);
      const float* ec = &els[(tb + j) * K_];
      const float* sc = &sls[(tb + j) * K_];
      float y = 0.f;
#pragma unroll
      for (int k = 0; k < K_; ++k) {
        m[k] = ft * m[k] + ec[k] * iv[j];
        y += sc[k] * m[k];
      }
      yp[(size_t)(tb + j) * D_] = f2bf(y);
    }
  }
}

// ---------------- row stats: rstd & -mu*rstd per row (1 wave/row) ---------
__global__ __launch_bounds__(256) void rowstat(const u16* __restrict__ y,
                                               float* __restrict__ rstd,
                                               float* __restrict__ mrs) {
  int row = blockIdx.x * 4 + (threadIdx.x >> 6);
  int l = threadIdx.x & 63;
  const u16* yr = y + (size_t)row * D_;
  float sum = 0.f, sq = 0.f;
#pragma unroll
  for (int j = 0; j < 2; ++j) {
    short8 raw = *(const short8*)(yr + l * 16 + j * 8);
#pragma unroll
    for (int q = 0; q < 8; ++q) {
      float f = bf2f((u16)raw[q]);
      sum += f;
      sq += f * f;
    }
  }
  for (int off = 32; off > 0; off >>= 1) {
    sum += __shfl_xor(sum, off);
    sq  += __shfl_xor(sq, off);
  }
  if (l == 0) {
    float mu = sum * (1.0f / D_);
    float var = sq * (1.0f / D_) - mu * mu;
    float rs = rsqrtf(var + 1e-5f);
    rstd[row] = rs;
    mrs[row] = -mu * rs;
  }
}

extern "C" void kernel_launch(void* const* d_in, const int* in_sizes, int n_in,
                              void* d_out, int out_size, void* d_ws, size_t ws_size,
                              hipStream_t stream) {
  const float* x     = (const float*)d_in[0];
  const float* Wi    = (const float*)d_in[1];
  const float* We    = (const float*)d_in[2];
  const float* Wf    = (const float*)d_in[3];
  const float* Ws    = (const float*)d_in[4];
  const float* gamma = (const float*)d_in[5];
  const float* beta  = (const float*)d_in[6];
  const float* Wo    = (const float*)d_in[7];
  float* out = (float*)d_out;

  char* p = (char*)d_ws;
  u16* xb   = (u16*)p;  p += (size_t)MROWS * D_ * 2;       // 16 MB
  u16* wib  = (u16*)p;  p += (size_t)D_ * D_ * 2;          // 2 MB
  u16* wfb  = (u16*)p;  p += (size_t)D_ * D_ * 2;          // 2 MB
  u16* wgb  = (u16*)p;  p += (size_t)D_ * D_ * 2;          // 2 MB (Wo*gamma)
  u16* ibb  = (u16*)p;  p += (size_t)MROWS * D_ * 2;       // 16 MB
  u16* zbb  = (u16*)p;  p += (size_t)MROWS * D_ * 2;       // 16 MB
  u16* ybb  = (u16*)p;  p += (size_t)MROWS * D_ * 2;       // 16 MB
  float* ebuf = (float*)p; p += (size_t)MROWS * K_ * 4;    // 512 KB
  float* sbuf = (float*)p; p += (size_t)MROWS * K_ * 4;    // 512 KB
  float* Asc  = (float*)p; p += (size_t)B_ * NC_ * K_ * D_ * 4;  // 16 MB
  float* Psc  = (float*)p; p += (size_t)B_ * NC_ * D_ * 4;       // 1 MB
  float* rstd = (float*)p; p += (size_t)MROWS * 4;         // 32 KB
  float* mrs  = (float*)p; p += (size_t)MROWS * 4;         // 32 KB
  float* ub   = (float*)p; p += (size_t)D_ * 4;            // 4 KB
  float* vb   = (float*)p; p += (size_t)D_ * 4;            // 4 KB

  cast_kernel<<<MROWS * D_ / 1024, 256, 0, stream>>>(x, xb, MROWS * D_);
  cast_kernel<<<D_ * D_ / 1024, 256, 0, stream>>>(Wi, wib, D_ * D_);
  cast_kernel<<<D_ * D_ / 1024, 256, 0, stream>>>(Wf, wfb, D_ * D_);
  prep_kernel<<<D_, 256, 0, stream>>>(Wo, gamma, beta, wgb, ub, vb);

  ring_fused<<<512, 512, 0, stream>>>(xb, wib, wfb, ibb, zbb);

  es_mfma<<<MROWS / 64, 256, 0, stream>>>(xb, We, Ws, ebuf, sbuf);

  scan_pass1<<<B_ * NC_ * 4, 256, 0, stream>>>(ibb, zbb, ebuf, Asc, Psc);
  scan_pass2<<<B_ * K_ * D_ / 256, 256, 0, stream>>>(Asc, Psc);
  scan_pass3<<<B_ * NC_ * 4, 256, 0, stream>>>(ibb, zbb, ebuf, sbuf, Asc, ybb);

  rowstat<<<MROWS / 4, 256, 0, stream>>>(ybb, rstd, mrs);

  gemm_bt_ln<<<512, 256, 0, stream>>>(ybb, wgb, out, rstd, mrs, ub, vb);
}